// Round 7
// baseline (228.920 us; speedup 1.0000x reference)
//
#include <hip/hip_runtime.h>
#include <hip/hip_bf16.h>

// Problem constants
#define Bdim 2
#define Nseq 2048
#define Dmod 1024
#define Hn   16
#define HDim 64

#define XN  (Bdim * Nseq * Dmod)        // 4,194,304
#define WQN (3 * Dmod * Dmod)           // 3,145,728
#define WON (Dmod * Dmod)               // 1,048,576

typedef __attribute__((ext_vector_type(8))) __bf16 bf16x8;
typedef __attribute__((ext_vector_type(4))) __bf16 bf16x4;
typedef __attribute__((ext_vector_type(4))) float  floatx4;

__device__ __forceinline__ floatx4 mfma16(bf16x8 a, bf16x8 b, floatx4 c) {
    return __builtin_amdgcn_mfma_f32_16x16x32_bf16(a, b, c, 0, 0, 0);
}

// native v_exp_f32 computes 2^x
__device__ __forceinline__ float exp2v(float x) {
    return __builtin_amdgcn_exp2f(x);
}

// async global->LDS, 16 B per lane.
__device__ __forceinline__ void async_copy16(__bf16* l, const __bf16* g) {
    __builtin_amdgcn_global_load_lds(
        (const __attribute__((address_space(1))) void*)g,
        (__attribute__((address_space(3))) void*)l,
        16, 0, 0);
}

// ---------------------------------------------------------------------------
// Kernel 0: fp32 -> bf16 conversion. 8 elems/thread: 2x float4 load (32 B)
// + 1x bf16x8 store (16 B/lane = coalescing sweet spot).
// ---------------------------------------------------------------------------
__global__ __launch_bounds__(256) void convert_kernel(
    const float* __restrict__ x, const float* __restrict__ wq,
    const float* __restrict__ wo,
    __bf16* __restrict__ xb, __bf16* __restrict__ wqb, __bf16* __restrict__ wob)
{
    int i = (blockIdx.x * 256 + threadIdx.x) * 8;
    const float* src;
    __bf16* dst;
    int off;
    if (i < XN)            { src = x;  dst = xb;  off = i; }
    else if (i < XN + WQN) { src = wq; dst = wqb; off = i - XN; }
    else                   { src = wo; dst = wob; off = i - XN - WQN; }
    float4 v0 = *(const float4*)(src + off);
    float4 v1 = *(const float4*)(src + off + 4);
    bf16x8 o;
    o[0] = (__bf16)v0.x; o[1] = (__bf16)v0.y; o[2] = (__bf16)v0.z; o[3] = (__bf16)v0.w;
    o[4] = (__bf16)v1.x; o[5] = (__bf16)v1.y; o[6] = (__bf16)v1.z; o[7] = (__bf16)v1.w;
    *(bf16x8*)(dst + off) = o;
}

// ---------------------------------------------------------------------------
// Kernel 1: QKV projection — PROVEN R1 version restored verbatim (43.4us).
// Static-dbuf (R6) was neutral-to-worse (44.8-45.7): implicit wave overlap
// already covers the staging latency at this occupancy (m99/m100 confirmed).
// Q third pre-scaled by C = hd^-0.5 * log2(e) (attention runs in log2 domain).
// ---------------------------------------------------------------------------
__global__ __launch_bounds__(256) void qkv_kernel(
    const __bf16* __restrict__ x, const __bf16* __restrict__ Wq,
    const float* __restrict__ bq,
    __bf16* __restrict__ qb, __bf16* __restrict__ kb, __bf16* __restrict__ vt)
{
    __shared__ __align__(16) __bf16 ldsA[128 * 32];
    __shared__ __align__(16) __bf16 ldsB[128 * 32];

    const int tid  = threadIdx.x;
    const int lane = tid & 63, l16 = lane & 15, quad = lane >> 4;
    const int wiw  = tid >> 6;
    const int wm   = wiw & 1, wn = wiw >> 1;

    const int bm = blockIdx.x & 31;             // 32 m-tiles (M=4096)
    const int bn = blockIdx.x >> 5;             // 24 n-tiles (N=3072)
    const int m0 = bm * 128, n0 = bn * 128;

    const int srow = tid >> 2;                  // staging row 0..63
    const int scol = (tid & 3) * 8;             // staging col {0,8,16,24}

    floatx4 z = {0.f, 0.f, 0.f, 0.f};
    floatx4 acc[4][4];
    #pragma unroll
    for (int mt = 0; mt < 4; ++mt)
        #pragma unroll
        for (int nt = 0; nt < 4; ++nt) acc[mt][nt] = z;

    const __bf16* ga = x  + (size_t)m0 * Dmod;
    const __bf16* gb = Wq + (size_t)n0 * Dmod;

    for (int k0 = 0; k0 < Dmod; k0 += 32) {
        async_copy16(&ldsA[srow * 32 + scol],        ga + (size_t)srow * Dmod + k0 + scol);
        async_copy16(&ldsA[(64 + srow) * 32 + scol], ga + (size_t)(64 + srow) * Dmod + k0 + scol);
        async_copy16(&ldsB[srow * 32 + scol],        gb + (size_t)srow * Dmod + k0 + scol);
        async_copy16(&ldsB[(64 + srow) * 32 + scol], gb + (size_t)(64 + srow) * Dmod + k0 + scol);
        __syncthreads();

        bf16x8 af[4], bfr[4];
        #pragma unroll
        for (int mt = 0; mt < 4; ++mt)
            af[mt] = *(const bf16x8*)&ldsA[(wm * 64 + mt * 16 + l16) * 32 + quad * 8];
        #pragma unroll
        for (int nt = 0; nt < 4; ++nt)
            bfr[nt] = *(const bf16x8*)&ldsB[(wn * 64 + nt * 16 + l16) * 32 + quad * 8];
        #pragma unroll
        for (int mt = 0; mt < 4; ++mt)
            #pragma unroll
            for (int nt = 0; nt < 4; ++nt)
                acc[mt][nt] = mfma16(af[mt], bfr[nt], acc[mt][nt]);
        __syncthreads();
    }

    const int nb    = n0 + wn * 64;
    const int which = nb >> 10;
    const int h     = (nb & 1023) >> 6;
    const int mw    = m0 + wm * 64;
    const int bi    = mw >> 11;
    const int pos0  = mw & (Nseq - 1);

    const float qscale = 0.18033688f;           // 0.125 * log2(e)

    #pragma unroll
    for (int nt = 0; nt < 4; ++nt) {
        float bias = bq[nb + nt * 16 + l16];
        int hd = nt * 16 + l16;
        #pragma unroll
        for (int mt = 0; mt < 4; ++mt)
            #pragma unroll
            for (int i = 0; i < 4; ++i) {
                int pos = pos0 + mt * 16 + quad * 4 + i;
                float r = acc[mt][nt][i] + bias;
                if (which == 0)
                    qb[((bi * Hn + h) * Nseq + pos) * HDim + hd] = (__bf16)(r * qscale);
                else if (which == 1)
                    kb[((bi * Hn + h) * Nseq + pos) * HDim + hd] = (__bf16)r;
                else
                    vt[((bi * Hn + h) * HDim + hd) * Nseq + pos] = (__bf16)r;
            }
    }
}

// ---------------------------------------------------------------------------
// Kernel 2: causal flash attention — R7: one barrier per K/V tile.
//  - K staged via global_load_lds (linear dest = wiw*512+lane*8, global
//    source col pre-swizzled (lane&7)^(lane>>3) — rule 21, same involution
//    the read side uses; mechanism correctness-proven in R2's qkv).
//  - Static ping-pong K buffers (ldsK0/ldsK1): buffer read at iter t is only
//    overwritten at t+2; the single end-of-iter barrier (implicit vmcnt(0))
//    publishes K(t+1) and retires K(t). Static names avoid R4's alias-drain.
//  - V read直接 to registers per wave (8x global_load_dwordx4 issued at iter
//    top, consumed in PV after QK+softmax ~300cyc of flight — T14). V's LDS
//    staging/roundtrip gone; 4x V L2 traffic is well within L2 BW.
// Keeps: 1024 blocks / 4 waves (4 blocks/CU), balanced qblk remap, folded-Q
// scale, ones-MFMA row-sum, defer-max THR=8, setprio.
// ---------------------------------------------------------------------------
#define ATTN_BODY(KC, KN, KT)                                                   \
  {                                                                             \
    const int k0c = (KT) * 64;                                                  \
    /* V fragments for this tile -> regs (early issue, used in PV) */           \
    bf16x8 vreg[4][2];                                                          \
    _Pragma("unroll")                                                           \
    for (int s = 0; s < 4; ++s) {                                               \
      const __bf16* vr = vs + (size_t)(s * 16 + l16) * Nseq + k0c;              \
      vreg[s][0] = *(const bf16x8*)(vr + quad * 8);                             \
      vreg[s][1] = *(const bf16x8*)(vr + 32 + quad * 8);                        \
    }                                                                           \
    /* stage next K tile into KN (async, in flight across whole body) */        \
    if ((KT) + 1 < nkt) {                                                       \
      const __bf16* knp = ks + ((size_t)((KT) + 1) * 64) * HDim;                \
      async_copy16(&KN[d0], knp + (size_t)r0 * HDim + sc0);                     \
      async_copy16(&KN[d1], knp + (size_t)r1 * HDim + sc0);                     \
    }                                                                           \
    const bool last = ((KT) == nkt - 1);                                        \
    floatx4 st[4];                                                              \
    __builtin_amdgcn_s_setprio(1);                                              \
    _Pragma("unroll")                                                           \
    for (int t = 0; t < 4; ++t) {                                               \
      const __bf16* kr = &KC[(t * 16 + l16) * 64];                              \
      bf16x8 kf0 = *(const bf16x8*)(kr + ((quad ^ swz) * 8));                   \
      bf16x8 kf1 = *(const bf16x8*)(kr + (((quad + 4) ^ swz) * 8));             \
      st[t] = mfma16(kf0, qf0, z);                                              \
      st[t] = mfma16(kf1, qf1, st[t]);                                          \
    }                                                                           \
    __builtin_amdgcn_s_setprio(0);                                              \
    float a[16];                                                                \
    _Pragma("unroll")                                                           \
    for (int t = 0; t < 4; ++t)                                                 \
      _Pragma("unroll")                                                         \
      for (int i = 0; i < 4; ++i) {                                             \
        float v = st[t][i];                                                     \
        if (last) {                                                             \
          int kidx = t * 16 + quad * 4 + i;                                     \
          v = (kidx <= wiw * 16 + l16) ? v : -1e30f;                            \
        }                                                                       \
        a[t * 4 + i] = v;                                                       \
      }                                                                         \
    float m0 = fmaxf(fmaxf(a[0],  a[1]),  a[2]);                                \
    float m1 = fmaxf(fmaxf(a[3],  a[4]),  a[5]);                                \
    float m2 = fmaxf(fmaxf(a[6],  a[7]),  a[8]);                                \
    float m3 = fmaxf(fmaxf(a[9],  a[10]), a[11]);                               \
    float m4 = fmaxf(fmaxf(a[12], a[13]), a[14]);                               \
    float mx = fmaxf(fmaxf(fmaxf(m0, m1), m2),                                  \
                     fmaxf(fmaxf(m3, m4), a[15]));                              \
    mx = fmaxf(mx, __shfl_xor(mx, 16));                                         \
    mx = fmaxf(mx, __shfl_xor(mx, 32));                                         \
    if (__any(mx > m_i + 8.0f)) {                                               \
      float mn    = fmaxf(m_i, mx);                                             \
      float alpha = exp2v(m_i - mn);                                            \
      _Pragma("unroll")                                                         \
      for (int s = 0; s < 4; ++s)                                               \
        _Pragma("unroll")                                                       \
        for (int i = 0; i < 4; ++i) o[s][i] *= alpha;                           \
      _Pragma("unroll")                                                         \
      for (int i = 0; i < 4; ++i) lacc[i] *= alpha;                             \
      m_i = mn;                                                                 \
    }                                                                           \
    float p[16];                                                                \
    _Pragma("unroll")                                                           \
    for (int j = 0; j < 16; ++j) p[j] = exp2v(a[j] - m_i);                      \
    _Pragma("unroll")                                                           \
    for (int t = 0; t < 4; ++t) {                                               \
      bf16x4 pk;                                                                \
      pk.x = (__bf16)p[t * 4 + 0]; pk.y = (__bf16)p[t * 4 + 1];                 \
      pk.z = (__bf16)p[t * 4 + 2]; pk.w = (__bf16)p[t * 4 + 3];                 \
      *(bf16x4*)(myp + l16 * 72 + t * 16 + quad * 4) = pk;                      \
    }                                                                           \
    asm volatile("s_waitcnt lgkmcnt(0)" ::: "memory");                          \
    bf16x8 pf0 = *(const bf16x8*)(myp + l16 * 72 + quad * 8);                   \
    bf16x8 pf1 = *(const bf16x8*)(myp + l16 * 72 + 32 + quad * 8);              \
    __builtin_amdgcn_s_setprio(1);                                              \
    lacc = mfma16(ones, pf0, lacc);                                             \
    lacc = mfma16(ones, pf1, lacc);                                             \
    _Pragma("unroll")                                                           \
    for (int s = 0; s < 4; ++s) {                                               \
      o[s] = mfma16(vreg[s][0], pf0, o[s]);                                     \
      o[s] = mfma16(vreg[s][1], pf1, o[s]);                                     \
    }                                                                           \
    __builtin_amdgcn_s_setprio(0);                                              \
    __syncthreads();                                                            \
  }

__global__ __launch_bounds__(256, 4) void attn_kernel(
    const __bf16* __restrict__ qbuf, const __bf16* __restrict__ kbuf,
    const __bf16* __restrict__ vtbuf, __bf16* __restrict__ aout)
{
    __shared__ __align__(16) __bf16 ldsK0[64 * 64];  // [key][d], swizzled cols
    __shared__ __align__(16) __bf16 ldsK1[64 * 64];
    __shared__ __align__(16) __bf16 ldsP[4][16 * 72];

    const int tid  = threadIdx.x;
    const int wiw  = tid >> 6;
    const int lane = tid & 63, l16 = lane & 15, quad = lane >> 4;
    const int b    = blockIdx.x;
    const int bh   = b & 31;                    // head: all 32 q-blocks of a
                                                // head share one XCD (b%8)
    // Balanced qblk remap: CU hosts blocks {i, i+256, i+512, i+768} ->
    // qblk {31-k, k, 23-k, 8+k}: per-CU work = 66 tiles for every k.
    const int g  = b >> 5;
    const int gk = g & 7, r4 = g >> 3;
    int qblk;
    if      (r4 == 0) qblk = 31 - gk;
    else if (r4 == 1) qblk = gk;
    else if (r4 == 2) qblk = 23 - gk;
    else              qblk = 8 + gk;

    const int q0 = qblk * 64 + wiw * 16;        // this wave's 16 queries

    const __bf16* qs = qbuf  + bh * Nseq * HDim;
    const __bf16* ks = kbuf  + bh * Nseq * HDim;
    const __bf16* vs = vtbuf + bh * HDim * Nseq;

    // K staging via global_load_lds: wave-linear dest, pre-swizzled source.
    // lane covers row r0 = wiw*8 + (lane>>3) (and r0+32), chunk lane&7.
    const int srl = lane >> 3;                  // 0..7
    const int scl = lane & 7;                   // 0..7
    const int r0  = wiw * 8 + srl;              // 0..31
    const int r1  = 32 + r0;                    // 32..63
    const int sc0 = (scl ^ srl) * 8;            // swizzled source col (elems)
    const int d0  = r0 * 64 + scl * 8;          // = wiw*512 + lane*8 (linear)
    const int d1  = r1 * 64 + scl * 8;

    // Q as B-operand: lane l16 = q row, k = d = quad*8+j  (pre-scaled by C)
    bf16x8 qf0 = *(const bf16x8*)(qs + (q0 + l16) * HDim + quad * 8);
    bf16x8 qf1 = *(const bf16x8*)(qs + (q0 + l16) * HDim + 32 + quad * 8);

    floatx4 z = {0.f, 0.f, 0.f, 0.f};
    floatx4 o[4];
    #pragma unroll
    for (int s = 0; s < 4; ++s) o[s] = z;
    floatx4 lacc = z;                           // row-sum accumulator (ones-MFMA)
    float m_i = -1e30f;                         // per-lane: q = q0 + l16

    bf16x8 ones;
    #pragma unroll
    for (int j = 0; j < 8; ++j) ones[j] = (__bf16)1.0f;

    const int nkt = qblk + 1;                   // 64-key tiles (uniform in block)
    __bf16* myp = ldsP[wiw];
    const int swz = l16 & 7;                    // read-side swizzle (row&7)

    // prologue: stage K tile 0 into ldsK0
    async_copy16(&ldsK0[d0], ks + (size_t)r0 * HDim + sc0);
    async_copy16(&ldsK0[d1], ks + (size_t)r1 * HDim + sc0);
    __syncthreads();

    int kt = 0;
    for (;;) {
        ATTN_BODY(ldsK0, ldsK1, kt);
        if (++kt >= nkt) break;
        ATTN_BODY(ldsK1, ldsK0, kt);
        if (++kt >= nkt) break;
    }

    // Epilogue: O^T tile s: row = d = s*16+quad*4+i, col = q = q0+l16
    const float inv = 1.0f / lacc[0];           // all lacc rows identical
    const int bi = bh >> 4, h = bh & 15;
    #pragma unroll
    for (int s = 0; s < 4; ++s) {
        bf16x4 ov;
        ov.x = (__bf16)(o[s][0] * inv); ov.y = (__bf16)(o[s][1] * inv);
        ov.z = (__bf16)(o[s][2] * inv); ov.w = (__bf16)(o[s][3] * inv);
        *(bf16x4*)(aout + ((size_t)(bi * Nseq + q0 + l16)) * Dmod
                   + h * 64 + s * 16 + quad * 4) = ov;
    }
}

// ---------------------------------------------------------------------------
// Kernel 3: output projection — PROVEN R1 version (BM=64 x BN=128, BK=32,
// single-buffer). Grid 64 m-tiles x 8 n-tiles = 512 blocks = 2 blocks/CU.
// ---------------------------------------------------------------------------
__global__ __launch_bounds__(256) void proj_kernel(
    const __bf16* __restrict__ ao, const __bf16* __restrict__ Wo,
    const float* __restrict__ bo, float* __restrict__ out)
{
    __shared__ __align__(16) __bf16 ldsA[64 * 32];
    __shared__ __align__(16) __bf16 ldsB[128 * 32];

    const int tid  = threadIdx.x;
    const int lane = tid & 63, l16 = lane & 15, quad = lane >> 4;
    const int wiw  = tid >> 6;
    const int wm   = wiw & 1, wn = wiw >> 1;

    const int bm = blockIdx.x & 63;             // 64 m-tiles (M=4096, BM=64)
    const int bn = blockIdx.x >> 6;             // 8 n-tiles (N=1024, BN=128)
    const int m0 = bm * 64, n0 = bn * 128;

    const int srow = tid >> 2;                  // 0..63
    const int scol = (tid & 3) * 8;             // {0,8,16,24}

    floatx4 z = {0.f, 0.f, 0.f, 0.f};
    floatx4 acc[2][4];
    #pragma unroll
    for (int mt = 0; mt < 2; ++mt)
        #pragma unroll
        for (int nt = 0; nt < 4; ++nt) acc[mt][nt] = z;

    const __bf16* ga = ao + (size_t)m0 * Dmod;
    const __bf16* gb = Wo + (size_t)n0 * Dmod;

    for (int k0 = 0; k0 < Dmod; k0 += 32) {
        async_copy16(&ldsA[srow * 32 + scol],        ga + (size_t)srow * Dmod + k0 + scol);
        async_copy16(&ldsB[srow * 32 + scol],        gb + (size_t)srow * Dmod + k0 + scol);
        async_copy16(&ldsB[(64 + srow) * 32 + scol], gb + (size_t)(64 + srow) * Dmod + k0 + scol);
        __syncthreads();

        bf16x8 af[2], bfr[4];
        #pragma unroll
        for (int mt = 0; mt < 2; ++mt)
            af[mt] = *(const bf16x8*)&ldsA[(wm * 32 + mt * 16 + l16) * 32 + quad * 8];
        #pragma unroll
        for (int nt = 0; nt < 4; ++nt)
            bfr[nt] = *(const bf16x8*)&ldsB[(wn * 64 + nt * 16 + l16) * 32 + quad * 8];
        #pragma unroll
        for (int mt = 0; mt < 2; ++mt)
            #pragma unroll
            for (int nt = 0; nt < 4; ++nt)
                acc[mt][nt] = mfma16(af[mt], bfr[nt], acc[mt][nt]);
        __syncthreads();
    }

    const int nb = n0 + wn * 64;
    const int mw = m0 + wm * 32;
    #pragma unroll
    for (int nt = 0; nt < 4; ++nt) {
        float bias = bo[nb + nt * 16 + l16];
        #pragma unroll
        for (int mt = 0; mt < 2; ++mt)
            #pragma unroll
            for (int i = 0; i < 4; ++i) {
                int m = mw + mt * 16 + quad * 4 + i;
                out[(size_t)m * Dmod + nb + nt * 16 + l16] = acc[mt][nt][i] + bias;
            }
    }
}

// ---------------------------------------------------------------------------
extern "C" void kernel_launch(void* const* d_in, const int* in_sizes, int n_in,
                              void* d_out, int out_size, void* d_ws, size_t ws_size,
                              hipStream_t stream) {
    const float* x  = (const float*)d_in[0];
    const float* Wq = (const float*)d_in[1];
    const float* bq = (const float*)d_in[2];
    const float* Wo = (const float*)d_in[3];
    const float* bo = (const float*)d_in[4];
    float* out = (float*)d_out;

    __bf16* ws  = (__bf16*)d_ws;
    __bf16* xb  = ws;
    __bf16* wqb = ws + (size_t)XN;
    __bf16* wob = wqb + (size_t)WQN;
    __bf16* qb  = wob + (size_t)WON;
    const size_t SZ = (size_t)Bdim * Hn * Nseq * HDim;
    __bf16* kb  = qb + SZ;
    __bf16* vt  = kb + SZ;
    __bf16* ao  = vt + SZ;

    // 8.38M elems / 8 per thread / 256 = 4096 blocks
    convert_kernel<<<dim3(4096), dim3(256), 0, stream>>>(x, Wq, Wo, xb, wqb, wob);
    // 32 m-tiles x 24 n-tiles = 768 blocks (proven 128x128 tile, BK=32)
    qkv_kernel<<<dim3(768), dim3(256), 0, stream>>>(xb, wqb, bq, qb, kb, vt);
    // 32 bh x 32 q-blocks = 1024 blocks, 4 waves each, balanced remap
    attn_kernel<<<dim3(1024), dim3(256), 0, stream>>>(qb, kb, vt, ao);
    // 64 m-tiles x 8 n-tiles = 512 blocks (2 blocks/CU)
    proj_kernel<<<dim3(512), dim3(256), 0, stream>>>(ao, wob, bo, out);
}

// Round 9
// 168.073 us; speedup vs baseline: 1.3620x; 1.3620x over previous
//
#include <hip/hip_runtime.h>
#include <hip/hip_bf16.h>

// Problem constants
#define Bdim 2
#define Nseq 2048
#define Dmod 1024
#define Hn   16
#define HDim 64

#define XN  (Bdim * Nseq * Dmod)        // 4,194,304
#define WQN (3 * Dmod * Dmod)           // 3,145,728
#define WON (Dmod * Dmod)               // 1,048,576

typedef __attribute__((ext_vector_type(8))) __bf16 bf16x8;
typedef __attribute__((ext_vector_type(4))) __bf16 bf16x4;
typedef __attribute__((ext_vector_type(4))) float  floatx4;

__device__ __forceinline__ floatx4 mfma16(bf16x8 a, bf16x8 b, floatx4 c) {
    return __builtin_amdgcn_mfma_f32_16x16x32_bf16(a, b, c, 0, 0, 0);
}

// native v_exp_f32 computes 2^x
__device__ __forceinline__ float exp2v(float x) {
    return __builtin_amdgcn_exp2f(x);
}

// async global->LDS, 16 B per lane (GEMMs only; attn uses swizzled ds_write).
__device__ __forceinline__ void async_copy16(__bf16* l, const __bf16* g) {
    __builtin_amdgcn_global_load_lds(
        (const __attribute__((address_space(1))) void*)g,
        (__attribute__((address_space(3))) void*)l,
        16, 0, 0);
}

// ---------------------------------------------------------------------------
// Kernel 0: fp32 -> bf16 conversion. 8 elems/thread: 2x float4 load (32 B)
// + 1x bf16x8 store (16 B/lane = coalescing sweet spot).
// ---------------------------------------------------------------------------
__global__ __launch_bounds__(256) void convert_kernel(
    const float* __restrict__ x, const float* __restrict__ wq,
    const float* __restrict__ wo,
    __bf16* __restrict__ xb, __bf16* __restrict__ wqb, __bf16* __restrict__ wob)
{
    int i = (blockIdx.x * 256 + threadIdx.x) * 8;
    const float* src;
    __bf16* dst;
    int off;
    if (i < XN)            { src = x;  dst = xb;  off = i; }
    else if (i < XN + WQN) { src = wq; dst = wqb; off = i - XN; }
    else                   { src = wo; dst = wob; off = i - XN - WQN; }
    float4 v0 = *(const float4*)(src + off);
    float4 v1 = *(const float4*)(src + off + 4);
    bf16x8 o;
    o[0] = (__bf16)v0.x; o[1] = (__bf16)v0.y; o[2] = (__bf16)v0.z; o[3] = (__bf16)v0.w;
    o[4] = (__bf16)v1.x; o[5] = (__bf16)v1.y; o[6] = (__bf16)v1.z; o[7] = (__bf16)v1.w;
    *(bf16x8*)(dst + off) = o;
}

// ---------------------------------------------------------------------------
// Kernel 1: QKV projection — PROVEN R1 version (m97-style 128x128, BK=32,
// single-buffer, bm-fast mapping). R7 micro-fix: the V-transposed epilogue
// path (which==2, wave-uniform) writes 4 CONSECUTIVE bf16 per lane ->
// packed bf16x4 store (8B, pos%4==0 aligned) instead of 4 scalar stores.
// Q third pre-scaled by C = hd^-0.5 * log2(e) (attention runs in log2 domain).
// ---------------------------------------------------------------------------
__global__ __launch_bounds__(256) void qkv_kernel(
    const __bf16* __restrict__ x, const __bf16* __restrict__ Wq,
    const float* __restrict__ bq,
    __bf16* __restrict__ qb, __bf16* __restrict__ kb, __bf16* __restrict__ vt)
{
    __shared__ __align__(16) __bf16 ldsA[128 * 32];
    __shared__ __align__(16) __bf16 ldsB[128 * 32];

    const int tid  = threadIdx.x;
    const int lane = tid & 63, l16 = lane & 15, quad = lane >> 4;
    const int wiw  = tid >> 6;
    const int wm   = wiw & 1, wn = wiw >> 1;

    const int bm = blockIdx.x & 31;             // 32 m-tiles (M=4096)
    const int bn = blockIdx.x >> 5;             // 24 n-tiles (N=3072)
    const int m0 = bm * 128, n0 = bn * 128;

    const int srow = tid >> 2;                  // staging row 0..63
    const int scol = (tid & 3) * 8;             // staging col {0,8,16,24}

    floatx4 z = {0.f, 0.f, 0.f, 0.f};
    floatx4 acc[4][4];
    #pragma unroll
    for (int mt = 0; mt < 4; ++mt)
        #pragma unroll
        for (int nt = 0; nt < 4; ++nt) acc[mt][nt] = z;

    const __bf16* ga = x  + (size_t)m0 * Dmod;
    const __bf16* gb = Wq + (size_t)n0 * Dmod;

    for (int k0 = 0; k0 < Dmod; k0 += 32) {
        async_copy16(&ldsA[srow * 32 + scol],        ga + (size_t)srow * Dmod + k0 + scol);
        async_copy16(&ldsA[(64 + srow) * 32 + scol], ga + (size_t)(64 + srow) * Dmod + k0 + scol);
        async_copy16(&ldsB[srow * 32 + scol],        gb + (size_t)srow * Dmod + k0 + scol);
        async_copy16(&ldsB[(64 + srow) * 32 + scol], gb + (size_t)(64 + srow) * Dmod + k0 + scol);
        __syncthreads();

        bf16x8 af[4], bfr[4];
        #pragma unroll
        for (int mt = 0; mt < 4; ++mt)
            af[mt] = *(const bf16x8*)&ldsA[(wm * 64 + mt * 16 + l16) * 32 + quad * 8];
        #pragma unroll
        for (int nt = 0; nt < 4; ++nt)
            bfr[nt] = *(const bf16x8*)&ldsB[(wn * 64 + nt * 16 + l16) * 32 + quad * 8];
        #pragma unroll
        for (int mt = 0; mt < 4; ++mt)
            #pragma unroll
            for (int nt = 0; nt < 4; ++nt)
                acc[mt][nt] = mfma16(af[mt], bfr[nt], acc[mt][nt]);
        __syncthreads();
    }

    const int nb    = n0 + wn * 64;
    const int which = nb >> 10;
    const int h     = (nb & 1023) >> 6;
    const int mw    = m0 + wm * 64;
    const int bi    = mw >> 11;
    const int pos0  = mw & (Nseq - 1);

    const float qscale = 0.18033688f;           // 0.125 * log2(e)

    #pragma unroll
    for (int nt = 0; nt < 4; ++nt) {
        float bias = bq[nb + nt * 16 + l16];
        int hd = nt * 16 + l16;
        #pragma unroll
        for (int mt = 0; mt < 4; ++mt) {
            if (which == 2) {
                // V^T: pos varies with i -> 4 consecutive bf16, one 8B store
                int pos = pos0 + mt * 16 + quad * 4;
                bf16x4 vv;
                vv.x = (__bf16)(acc[mt][nt][0] + bias);
                vv.y = (__bf16)(acc[mt][nt][1] + bias);
                vv.z = (__bf16)(acc[mt][nt][2] + bias);
                vv.w = (__bf16)(acc[mt][nt][3] + bias);
                *(bf16x4*)(vt + ((size_t)((bi * Hn + h) * HDim + hd)) * Nseq + pos) = vv;
            } else {
                #pragma unroll
                for (int i = 0; i < 4; ++i) {
                    int pos = pos0 + mt * 16 + quad * 4 + i;
                    float r = acc[mt][nt][i] + bias;
                    if (which == 0)
                        qb[((bi * Hn + h) * Nseq + pos) * HDim + hd] = (__bf16)(r * qscale);
                    else
                        kb[((bi * Hn + h) * Nseq + pos) * HDim + hd] = (__bf16)r;
                }
            }
        }
    }
}

// ---------------------------------------------------------------------------
// Kernel 2: causal flash attention, block-cooperative — PROVEN R1 version
// restored verbatim (38.5us). Every structural deviation regressed:
// no-LDS (R3: 126us, latency-bound), 32q/wave (R5: 49us, occupancy-starved),
// 1-barrier ping-pong + V-in-reg (R7: 95us, scratch spill + exposed V lat).
// The R1 design's full-tile-body register prefetch + 4 blocks/CU is matched
// to the latency-hiding budget. Keeps: balanced per-CU qblk remap, scale
// folded into Q, ones-MFMA row-sum, defer-max THR=8, setprio.
// ---------------------------------------------------------------------------
__global__ __launch_bounds__(256, 4) void attn_kernel(
    const __bf16* __restrict__ qbuf, const __bf16* __restrict__ kbuf,
    const __bf16* __restrict__ vtbuf, __bf16* __restrict__ aout)
{
    __shared__ __align__(16) __bf16 ldsK[64 * 64];   // [key][d], swizzled
    __shared__ __align__(16) __bf16 ldsV[64 * 64];   // [d][key], swizzled
    __shared__ __align__(16) __bf16 ldsP[4][16 * 72];

    const int tid  = threadIdx.x;
    const int wiw  = tid >> 6;
    const int lane = tid & 63, l16 = lane & 15, quad = lane >> 4;
    const int b    = blockIdx.x;
    const int bh   = b & 31;                    // head: all 32 q-blocks of a
                                                // head share one XCD (b%8)
    // Balanced qblk remap: CU hosts blocks {i, i+256, i+512, i+768} ->
    // g-groups {k, k+8, k+16, k+24} -> qblk {31-k, k, 23-k, 8+k},
    // per-CU work = (32-k)+(k+1)+(24-k)+(9+k) = 66 tiles for every k.
    const int g  = b >> 5;
    const int gk = g & 7, r4 = g >> 3;
    int qblk;
    if      (r4 == 0) qblk = 31 - gk;
    else if (r4 == 1) qblk = gk;
    else if (r4 == 2) qblk = 23 - gk;
    else              qblk = 8 + gk;

    const int q0 = qblk * 64 + wiw * 16;        // this wave's 16 queries

    const __bf16* qs = qbuf  + bh * Nseq * HDim;
    const __bf16* ks = kbuf  + bh * Nseq * HDim;
    const __bf16* vs = vtbuf + bh * HDim * Nseq;

    // staging coords: thread handles rows sr, sr+32; 16B block sb
    const int sr  = tid >> 3;                   // 0..31
    const int sb  = tid & 7;                    // 0..7
    const int swr = (sb ^ (sr & 7)) * 8;        // swizzled block offset (elems)
    const int wk0 = sr * 64 + swr;              // (sr+32)&7 == sr&7
    const int wk1 = (sr + 32) * 64 + swr;

    // Q as B-operand: lane l16 = q row, k = d = quad*8+j  (pre-scaled by C)
    bf16x8 qf0 = *(const bf16x8*)(qs + (q0 + l16) * HDim + quad * 8);
    bf16x8 qf1 = *(const bf16x8*)(qs + (q0 + l16) * HDim + 32 + quad * 8);

    floatx4 z = {0.f, 0.f, 0.f, 0.f};
    floatx4 o[4];
    #pragma unroll
    for (int s = 0; s < 4; ++s) o[s] = z;
    floatx4 lacc = z;                           // row-sum accumulator (ones-MFMA)
    float m_i = -1e30f;                         // per-lane: q = q0 + l16

    bf16x8 ones;
    #pragma unroll
    for (int j = 0; j < 8; ++j) ones[j] = (__bf16)1.0f;

    const int   nkt = qblk + 1;                 // 64-key tiles (uniform in block)
    __bf16* myp = ldsP[wiw];
    const int swz = l16 & 7;                    // read-side swizzle (row&7)

    // prefetch tile 0 into registers
    float4 rk0 = *(const float4*)(ks + (size_t)sr * HDim + sb * 8);
    float4 rk1 = *(const float4*)(ks + (size_t)(sr + 32) * HDim + sb * 8);
    float4 rv0 = *(const float4*)(vs + (size_t)sr * Nseq + sb * 8);
    float4 rv1 = *(const float4*)(vs + (size_t)(sr + 32) * Nseq + sb * 8);

    for (int kt = 0; kt < nkt; ++kt) {
        // issue next tile's global loads first (in flight during compute)
        float4 nk0 = {}, nk1 = {}, nv0 = {}, nv1 = {};
        if (kt + 1 < nkt) {
            const int k0n = (kt + 1) * 64;
            nk0 = *(const float4*)(ks + (size_t)(k0n + sr) * HDim + sb * 8);
            nk1 = *(const float4*)(ks + (size_t)(k0n + sr + 32) * HDim + sb * 8);
            nv0 = *(const float4*)(vs + (size_t)sr * Nseq + k0n + sb * 8);
            nv1 = *(const float4*)(vs + (size_t)(sr + 32) * Nseq + k0n + sb * 8);
        }

        // write current tile to LDS (swizzled)
        *(float4*)&ldsK[wk0] = rk0;
        *(float4*)&ldsK[wk1] = rk1;
        *(float4*)&ldsV[wk0] = rv0;
        *(float4*)&ldsV[wk1] = rv1;
        __syncthreads();

        const bool last = (kt == nkt - 1);

        // S^T: 4 subtiles of 16 keys. A=K (m=key), B=Q (n=q).
        floatx4 st[4];
        __builtin_amdgcn_s_setprio(1);
        #pragma unroll
        for (int t = 0; t < 4; ++t) {
            const __bf16* kr = &ldsK[(t * 16 + l16) * 64];
            bf16x8 kf0 = *(const bf16x8*)(kr + ((quad ^ swz) * 8));
            bf16x8 kf1 = *(const bf16x8*)(kr + (((quad + 4) ^ swz) * 8));
            st[t] = mfma16(kf0, qf0, z);
            st[t] = mfma16(kf1, qf1, st[t]);
        }
        __builtin_amdgcn_s_setprio(0);

        // scores (log2 domain, scale pre-folded into Q);
        // lane holds keys {16t+quad*4+i} for q=q0+l16
        float a[16];
        #pragma unroll
        for (int t = 0; t < 4; ++t)
            #pragma unroll
            for (int i = 0; i < 4; ++i) {
                float v = st[t][i];
                if (last) {
                    int kidx = t * 16 + quad * 4 + i;      // key - k0
                    v = (kidx <= wiw * 16 + l16) ? v : -1e30f;
                }
                a[t * 4 + i] = v;
            }

        // row max: max3-shaped tree + 2 cross-quad shuffles
        float m0 = fmaxf(fmaxf(a[0],  a[1]),  a[2]);
        float m1 = fmaxf(fmaxf(a[3],  a[4]),  a[5]);
        float m2 = fmaxf(fmaxf(a[6],  a[7]),  a[8]);
        float m3 = fmaxf(fmaxf(a[9],  a[10]), a[11]);
        float m4 = fmaxf(fmaxf(a[12], a[13]), a[14]);
        float mx = fmaxf(fmaxf(fmaxf(m0, m1), m2),
                         fmaxf(fmaxf(m3, m4), a[15]));
        mx = fmaxf(mx, __shfl_xor(mx, 16));
        mx = fmaxf(mx, __shfl_xor(mx, 32));

        // defer-max: only rescale when some row's max grew by >8 (log2 units);
        // otherwise keep m_i, P bounded by 2^8 = 256 (fine in bf16/f32).
        if (__any(mx > m_i + 8.0f)) {
            float mn    = fmaxf(m_i, mx);
            float alpha = exp2v(m_i - mn);
            #pragma unroll
            for (int s = 0; s < 4; ++s)
                #pragma unroll
                for (int i = 0; i < 4; ++i) o[s][i] *= alpha;
            #pragma unroll
            for (int i = 0; i < 4; ++i) lacc[i] *= alpha;
            m_i = mn;
        }

        float p[16];
        #pragma unroll
        for (int j = 0; j < 16; ++j) p[j] = exp2v(a[j] - m_i);

        // P: C-layout -> LDS -> B-layout (per-wave region, stride 72)
        #pragma unroll
        for (int t = 0; t < 4; ++t) {
            bf16x4 pk;
            pk.x = (__bf16)p[t * 4 + 0]; pk.y = (__bf16)p[t * 4 + 1];
            pk.z = (__bf16)p[t * 4 + 2]; pk.w = (__bf16)p[t * 4 + 3];
            *(bf16x4*)(myp + l16 * 72 + t * 16 + quad * 4) = pk;
        }
        asm volatile("s_waitcnt lgkmcnt(0)" ::: "memory");
        bf16x8 pf0 = *(const bf16x8*)(myp + l16 * 72 + quad * 8);
        bf16x8 pf1 = *(const bf16x8*)(myp + l16 * 72 + 32 + quad * 8);

        __builtin_amdgcn_s_setprio(1);
        // row-sum via ones-MFMA: lacc rows all = sum_k P[q][k] (bf16 P —
        // consistent with the P used for O, so O/l is a true weighted mean)
        lacc = mfma16(ones, pf0, lacc);
        lacc = mfma16(ones, pf1, lacc);

        // O^T += V^T P^T : A=V^T (m=d, k=key) from LDS (swizzled)
        #pragma unroll
        for (int s = 0; s < 4; ++s) {
            const __bf16* vr = &ldsV[(s * 16 + l16) * 64];
            bf16x8 vf0 = *(const bf16x8*)(vr + ((quad ^ swz) * 8));
            bf16x8 vf1 = *(const bf16x8*)(vr + (((quad + 4) ^ swz) * 8));
            o[s] = mfma16(vf0, pf0, o[s]);
            o[s] = mfma16(vf1, pf1, o[s]);
        }
        __builtin_amdgcn_s_setprio(0);
        __syncthreads();                        // all waves done with K/V tile

        rk0 = nk0; rk1 = nk1; rv0 = nv0; rv1 = nv1;
    }

    // Epilogue: O^T tile s: row = d = s*16+quad*4+i, col = q = q0+l16
    const float inv = 1.0f / lacc[0];           // all lacc rows identical
    const int bi = bh >> 4, h = bh & 15;
    #pragma unroll
    for (int s = 0; s < 4; ++s) {
        bf16x4 ov;
        ov.x = (__bf16)(o[s][0] * inv); ov.y = (__bf16)(o[s][1] * inv);
        ov.z = (__bf16)(o[s][2] * inv); ov.w = (__bf16)(o[s][3] * inv);
        *(bf16x4*)(aout + ((size_t)(bi * Nseq + q0 + l16)) * Dmod
                   + h * 64 + s * 16 + quad * 4) = ov;
    }
}

// ---------------------------------------------------------------------------
// Kernel 3: output projection — PROVEN R1 version (BM=64 x BN=128, BK=32,
// single-buffer). Grid 64 m-tiles x 8 n-tiles = 512 blocks = 2 blocks/CU.
// ---------------------------------------------------------------------------
__global__ __launch_bounds__(256) void proj_kernel(
    const __bf16* __restrict__ ao, const __bf16* __restrict__ Wo,
    const float* __restrict__ bo, float* __restrict__ out)
{
    __shared__ __align__(16) __bf16 ldsA[64 * 32];
    __shared__ __align__(16) __bf16 ldsB[128 * 32];

    const int tid  = threadIdx.x;
    const int lane = tid & 63, l16 = lane & 15, quad = lane >> 4;
    const int wiw  = tid >> 6;
    const int wm   = wiw & 1, wn = wiw >> 1;

    const int bm = blockIdx.x & 63;             // 64 m-tiles (M=4096, BM=64)
    const int bn = blockIdx.x >> 6;             // 8 n-tiles (N=1024, BN=128)
    const int m0 = bm * 64, n0 = bn * 128;

    const int srow = tid >> 2;                  // 0..63
    const int scol = (tid & 3) * 8;             // {0,8,16,24}

    floatx4 z = {0.f, 0.f, 0.f, 0.f};
    floatx4 acc[2][4];
    #pragma unroll
    for (int mt = 0; mt < 2; ++mt)
        #pragma unroll
        for (int nt = 0; nt < 4; ++nt) acc[mt][nt] = z;

    const __bf16* ga = ao + (size_t)m0 * Dmod;
    const __bf16* gb = Wo + (size_t)n0 * Dmod;

    for (int k0 = 0; k0 < Dmod; k0 += 32) {
        async_copy16(&ldsA[srow * 32 + scol],        ga + (size_t)srow * Dmod + k0 + scol);
        async_copy16(&ldsB[srow * 32 + scol],        gb + (size_t)srow * Dmod + k0 + scol);
        async_copy16(&ldsB[(64 + srow) * 32 + scol], gb + (size_t)(64 + srow) * Dmod + k0 + scol);
        __syncthreads();

        bf16x8 af[2], bfr[4];
        #pragma unroll
        for (int mt = 0; mt < 2; ++mt)
            af[mt] = *(const bf16x8*)&ldsA[(wm * 32 + mt * 16 + l16) * 32 + quad * 8];
        #pragma unroll
        for (int nt = 0; nt < 4; ++nt)
            bfr[nt] = *(const bf16x8*)&ldsB[(wn * 64 + nt * 16 + l16) * 32 + quad * 8];
        #pragma unroll
        for (int mt = 0; mt < 2; ++mt)
            #pragma unroll
            for (int nt = 0; nt < 4; ++nt)
                acc[mt][nt] = mfma16(af[mt], bfr[nt], acc[mt][nt]);
        __syncthreads();
    }

    const int nb = n0 + wn * 64;
    const int mw = m0 + wm * 32;
    #pragma unroll
    for (int nt = 0; nt < 4; ++nt) {
        float bias = bo[nb + nt * 16 + l16];
        #pragma unroll
        for (int mt = 0; mt < 2; ++mt)
            #pragma unroll
            for (int i = 0; i < 4; ++i) {
                int m = mw + mt * 16 + quad * 4 + i;
                out[(size_t)m * Dmod + nb + nt * 16 + l16] = acc[mt][nt][i] + bias;
            }
    }
}

// ---------------------------------------------------------------------------
extern "C" void kernel_launch(void* const* d_in, const int* in_sizes, int n_in,
                              void* d_out, int out_size, void* d_ws, size_t ws_size,
                              hipStream_t stream) {
    const float* x  = (const float*)d_in[0];
    const float* Wq = (const float*)d_in[1];
    const float* bq = (const float*)d_in[2];
    const float* Wo = (const float*)d_in[3];
    const float* bo = (const float*)d_in[4];
    float* out = (float*)d_out;

    __bf16* ws  = (__bf16*)d_ws;
    __bf16* xb  = ws;
    __bf16* wqb = ws + (size_t)XN;
    __bf16* wob = wqb + (size_t)WQN;
    __bf16* qb  = wob + (size_t)WON;
    const size_t SZ = (size_t)Bdim * Hn * Nseq * HDim;
    __bf16* kb  = qb + SZ;
    __bf16* vt  = kb + SZ;
    __bf16* ao  = vt + SZ;

    // 8.38M elems / 8 per thread / 256 = 4096 blocks
    convert_kernel<<<dim3(4096), dim3(256), 0, stream>>>(x, Wq, Wo, xb, wqb, wob);
    // 32 m-tiles x 24 n-tiles = 768 blocks (proven 128x128 tile, BK=32)
    qkv_kernel<<<dim3(768), dim3(256), 0, stream>>>(xb, wqb, bq, qb, kb, vt);
    // 32 bh x 32 q-blocks = 1024 blocks, 4 waves each, balanced remap
    attn_kernel<<<dim3(1024), dim3(256), 0, stream>>>(qb, kb, vt, ao);
    // 64 m-tiles x 8 n-tiles = 512 blocks (2 blocks/CU)
    proj_kernel<<<dim3(512), dim3(256), 0, stream>>>(ao, wob, bo, out);
}

// Round 10
// 166.637 us; speedup vs baseline: 1.3738x; 1.0086x over previous
//
#include <hip/hip_runtime.h>
#include <hip/hip_bf16.h>

// Problem constants
#define Bdim 2
#define Nseq 2048
#define Dmod 1024
#define Hn   16
#define HDim 64

#define XN  (Bdim * Nseq * Dmod)        // 4,194,304
#define WQN (3 * Dmod * Dmod)           // 3,145,728
#define WON (Dmod * Dmod)               // 1,048,576

typedef __attribute__((ext_vector_type(8))) __bf16 bf16x8;
typedef __attribute__((ext_vector_type(4))) __bf16 bf16x4;
typedef __attribute__((ext_vector_type(4))) float  floatx4;

__device__ __forceinline__ floatx4 mfma16(bf16x8 a, bf16x8 b, floatx4 c) {
    return __builtin_amdgcn_mfma_f32_16x16x32_bf16(a, b, c, 0, 0, 0);
}

// native v_exp_f32 computes 2^x
__device__ __forceinline__ float exp2v(float x) {
    return __builtin_amdgcn_exp2f(x);
}

// async global->LDS, 16 B per lane (GEMMs only; attn uses swizzled ds_write).
__device__ __forceinline__ void async_copy16(__bf16* l, const __bf16* g) {
    __builtin_amdgcn_global_load_lds(
        (const __attribute__((address_space(1))) void*)g,
        (__attribute__((address_space(3))) void*)l,
        16, 0, 0);
}

// ---------------------------------------------------------------------------
// Kernel 0: fp32 -> bf16 conversion. 8 elems/thread: 2x float4 load (32 B)
// + 1x bf16x8 store (16 B/lane = coalescing sweet spot).
// ---------------------------------------------------------------------------
__global__ __launch_bounds__(256) void convert_kernel(
    const float* __restrict__ x, const float* __restrict__ wq,
    const float* __restrict__ wo,
    __bf16* __restrict__ xb, __bf16* __restrict__ wqb, __bf16* __restrict__ wob)
{
    int i = (blockIdx.x * 256 + threadIdx.x) * 8;
    const float* src;
    __bf16* dst;
    int off;
    if (i < XN)            { src = x;  dst = xb;  off = i; }
    else if (i < XN + WQN) { src = wq; dst = wqb; off = i - XN; }
    else                   { src = wo; dst = wob; off = i - XN - WQN; }
    float4 v0 = *(const float4*)(src + off);
    float4 v1 = *(const float4*)(src + off + 4);
    bf16x8 o;
    o[0] = (__bf16)v0.x; o[1] = (__bf16)v0.y; o[2] = (__bf16)v0.z; o[3] = (__bf16)v0.w;
    o[4] = (__bf16)v1.x; o[5] = (__bf16)v1.y; o[6] = (__bf16)v1.z; o[7] = (__bf16)v1.w;
    *(bf16x8*)(dst + off) = o;
}

// ---------------------------------------------------------------------------
// Kernel 1: QKV projection — PROVEN R1 structure (m97-style 128x128, BK=32,
// single-buffer, bm-fast mapping). Store packing:
//  - V^T (which==2): bf16x4 packed store (R9, proven −5.7us total).
//  - Q/K (R10): PERMUTED-hd layout hd -> l16*4 + nt, making each lane's 4
//    nt-values consecutive -> one 8B store per (mt,i) instead of 4 scalar
//    2B stores (64 -> 16 store instrs, fully coalesced lines). Correct by
//    construction: hd is the CONTRACTED dim of QK^T and both Q and K carry
//    the same permutation — attn reads rows byte-linearly, so fragment
//    element (quad,j) pairs identically on both sides and the permutation
//    cancels in the dot product. V stays canonical (its hd is an output dim
//    feeding proj). Zero changes needed in attn.
// Q third pre-scaled by C = hd^-0.5 * log2(e) (attention runs in log2 domain).
// ---------------------------------------------------------------------------
__global__ __launch_bounds__(256) void qkv_kernel(
    const __bf16* __restrict__ x, const __bf16* __restrict__ Wq,
    const float* __restrict__ bq,
    __bf16* __restrict__ qb, __bf16* __restrict__ kb, __bf16* __restrict__ vt)
{
    __shared__ __align__(16) __bf16 ldsA[128 * 32];
    __shared__ __align__(16) __bf16 ldsB[128 * 32];

    const int tid  = threadIdx.x;
    const int lane = tid & 63, l16 = lane & 15, quad = lane >> 4;
    const int wiw  = tid >> 6;
    const int wm   = wiw & 1, wn = wiw >> 1;

    const int bm = blockIdx.x & 31;             // 32 m-tiles (M=4096)
    const int bn = blockIdx.x >> 5;             // 24 n-tiles (N=3072)
    const int m0 = bm * 128, n0 = bn * 128;

    const int srow = tid >> 2;                  // staging row 0..63
    const int scol = (tid & 3) * 8;             // staging col {0,8,16,24}

    floatx4 z = {0.f, 0.f, 0.f, 0.f};
    floatx4 acc[4][4];
    #pragma unroll
    for (int mt = 0; mt < 4; ++mt)
        #pragma unroll
        for (int nt = 0; nt < 4; ++nt) acc[mt][nt] = z;

    const __bf16* ga = x  + (size_t)m0 * Dmod;
    const __bf16* gb = Wq + (size_t)n0 * Dmod;

    for (int k0 = 0; k0 < Dmod; k0 += 32) {
        async_copy16(&ldsA[srow * 32 + scol],        ga + (size_t)srow * Dmod + k0 + scol);
        async_copy16(&ldsA[(64 + srow) * 32 + scol], ga + (size_t)(64 + srow) * Dmod + k0 + scol);
        async_copy16(&ldsB[srow * 32 + scol],        gb + (size_t)srow * Dmod + k0 + scol);
        async_copy16(&ldsB[(64 + srow) * 32 + scol], gb + (size_t)(64 + srow) * Dmod + k0 + scol);
        __syncthreads();

        bf16x8 af[4], bfr[4];
        #pragma unroll
        for (int mt = 0; mt < 4; ++mt)
            af[mt] = *(const bf16x8*)&ldsA[(wm * 64 + mt * 16 + l16) * 32 + quad * 8];
        #pragma unroll
        for (int nt = 0; nt < 4; ++nt)
            bfr[nt] = *(const bf16x8*)&ldsB[(wn * 64 + nt * 16 + l16) * 32 + quad * 8];
        #pragma unroll
        for (int mt = 0; mt < 4; ++mt)
            #pragma unroll
            for (int nt = 0; nt < 4; ++nt)
                acc[mt][nt] = mfma16(af[mt], bfr[nt], acc[mt][nt]);
        __syncthreads();
    }

    const int nb    = n0 + wn * 64;
    const int which = nb >> 10;
    const int h     = (nb & 1023) >> 6;
    const int mw    = m0 + wm * 64;
    const int bi    = mw >> 11;
    const int pos0  = mw & (Nseq - 1);

    const float qscale = 0.18033688f;           // 0.125 * log2(e)

    float bias4[4];
    #pragma unroll
    for (int nt = 0; nt < 4; ++nt) bias4[nt] = bq[nb + nt * 16 + l16];

    if (which == 2) {
        // V^T: canonical layout; pos varies with i -> packed bf16x4 store
        #pragma unroll
        for (int nt = 0; nt < 4; ++nt) {
            int hd = nt * 16 + l16;
            #pragma unroll
            for (int mt = 0; mt < 4; ++mt) {
                int pos = pos0 + mt * 16 + quad * 4;
                bf16x4 vv;
                vv.x = (__bf16)(acc[mt][nt][0] + bias4[nt]);
                vv.y = (__bf16)(acc[mt][nt][1] + bias4[nt]);
                vv.z = (__bf16)(acc[mt][nt][2] + bias4[nt]);
                vv.w = (__bf16)(acc[mt][nt][3] + bias4[nt]);
                *(bf16x4*)(vt + ((size_t)((bi * Hn + h) * HDim + hd)) * Nseq + pos) = vv;
            }
        }
    } else {
        // Q/K: permuted-hd layout (hd -> l16*4 + nt); lane's 4 nt-values
        // are consecutive -> one aligned 8B store per (mt,i).
        __bf16* dst = (which == 0) ? qb : kb;
        const float sc = (which == 0) ? qscale : 1.0f;
        #pragma unroll
        for (int mt = 0; mt < 4; ++mt)
            #pragma unroll
            for (int i = 0; i < 4; ++i) {
                int pos = pos0 + mt * 16 + quad * 4 + i;
                bf16x4 qk;
                qk.x = (__bf16)((acc[mt][0][i] + bias4[0]) * sc);
                qk.y = (__bf16)((acc[mt][1][i] + bias4[1]) * sc);
                qk.z = (__bf16)((acc[mt][2][i] + bias4[2]) * sc);
                qk.w = (__bf16)((acc[mt][3][i] + bias4[3]) * sc);
                *(bf16x4*)(dst + ((size_t)((bi * Hn + h) * Nseq + pos)) * HDim
                           + l16 * 4) = qk;
            }
    }
}

// ---------------------------------------------------------------------------
// Kernel 2: causal flash attention, block-cooperative — PROVEN R1 version
// (38.5us). Q/K rows arrive in permuted-hd order (see qkv); all reads here
// are byte-linear over the contracted dim, so no changes are needed — the
// permutation cancels between the Q and K fragments inside QK^T. V is
// canonical (its hd indexes output rows). Every structural deviation
// regressed (R3 no-LDS, R5 32q/wave, R7 1-barrier ping-pong); this design's
// full-tile-body register prefetch + 4 blocks/CU matches the latency budget.
// ---------------------------------------------------------------------------
__global__ __launch_bounds__(256, 4) void attn_kernel(
    const __bf16* __restrict__ qbuf, const __bf16* __restrict__ kbuf,
    const __bf16* __restrict__ vtbuf, __bf16* __restrict__ aout)
{
    __shared__ __align__(16) __bf16 ldsK[64 * 64];   // [key][d], swizzled
    __shared__ __align__(16) __bf16 ldsV[64 * 64];   // [d][key], swizzled
    __shared__ __align__(16) __bf16 ldsP[4][16 * 72];

    const int tid  = threadIdx.x;
    const int wiw  = tid >> 6;
    const int lane = tid & 63, l16 = lane & 15, quad = lane >> 4;
    const int b    = blockIdx.x;
    const int bh   = b & 31;                    // head: all 32 q-blocks of a
                                                // head share one XCD (b%8)
    // Balanced qblk remap: CU hosts blocks {i, i+256, i+512, i+768} ->
    // g-groups {k, k+8, k+16, k+24} -> qblk {31-k, k, 23-k, 8+k},
    // per-CU work = (32-k)+(k+1)+(24-k)+(9+k) = 66 tiles for every k.
    const int g  = b >> 5;
    const int gk = g & 7, r4 = g >> 3;
    int qblk;
    if      (r4 == 0) qblk = 31 - gk;
    else if (r4 == 1) qblk = gk;
    else if (r4 == 2) qblk = 23 - gk;
    else              qblk = 8 + gk;

    const int q0 = qblk * 64 + wiw * 16;        // this wave's 16 queries

    const __bf16* qs = qbuf  + bh * Nseq * HDim;
    const __bf16* ks = kbuf  + bh * Nseq * HDim;
    const __bf16* vs = vtbuf + bh * HDim * Nseq;

    // staging coords: thread handles rows sr, sr+32; 16B block sb
    const int sr  = tid >> 3;                   // 0..31
    const int sb  = tid & 7;                    // 0..7
    const int swr = (sb ^ (sr & 7)) * 8;        // swizzled block offset (elems)
    const int wk0 = sr * 64 + swr;              // (sr+32)&7 == sr&7
    const int wk1 = (sr + 32) * 64 + swr;

    // Q as B-operand: lane l16 = q row, k = permuted-hd = quad*8+j
    bf16x8 qf0 = *(const bf16x8*)(qs + (q0 + l16) * HDim + quad * 8);
    bf16x8 qf1 = *(const bf16x8*)(qs + (q0 + l16) * HDim + 32 + quad * 8);

    floatx4 z = {0.f, 0.f, 0.f, 0.f};
    floatx4 o[4];
    #pragma unroll
    for (int s = 0; s < 4; ++s) o[s] = z;
    floatx4 lacc = z;                           // row-sum accumulator (ones-MFMA)
    float m_i = -1e30f;                         // per-lane: q = q0 + l16

    bf16x8 ones;
    #pragma unroll
    for (int j = 0; j < 8; ++j) ones[j] = (__bf16)1.0f;

    const int   nkt = qblk + 1;                 // 64-key tiles (uniform in block)
    __bf16* myp = ldsP[wiw];
    const int swz = l16 & 7;                    // read-side swizzle (row&7)

    // prefetch tile 0 into registers
    float4 rk0 = *(const float4*)(ks + (size_t)sr * HDim + sb * 8);
    float4 rk1 = *(const float4*)(ks + (size_t)(sr + 32) * HDim + sb * 8);
    float4 rv0 = *(const float4*)(vs + (size_t)sr * Nseq + sb * 8);
    float4 rv1 = *(const float4*)(vs + (size_t)(sr + 32) * Nseq + sb * 8);

    for (int kt = 0; kt < nkt; ++kt) {
        // issue next tile's global loads first (in flight during compute)
        float4 nk0 = {}, nk1 = {}, nv0 = {}, nv1 = {};
        if (kt + 1 < nkt) {
            const int k0n = (kt + 1) * 64;
            nk0 = *(const float4*)(ks + (size_t)(k0n + sr) * HDim + sb * 8);
            nk1 = *(const float4*)(ks + (size_t)(k0n + sr + 32) * HDim + sb * 8);
            nv0 = *(const float4*)(vs + (size_t)sr * Nseq + k0n + sb * 8);
            nv1 = *(const float4*)(vs + (size_t)(sr + 32) * Nseq + k0n + sb * 8);
        }

        // write current tile to LDS (swizzled)
        *(float4*)&ldsK[wk0] = rk0;
        *(float4*)&ldsK[wk1] = rk1;
        *(float4*)&ldsV[wk0] = rv0;
        *(float4*)&ldsV[wk1] = rv1;
        __syncthreads();

        const bool last = (kt == nkt - 1);

        // S^T: 4 subtiles of 16 keys. A=K (m=key), B=Q (n=q).
        floatx4 st[4];
        __builtin_amdgcn_s_setprio(1);
        #pragma unroll
        for (int t = 0; t < 4; ++t) {
            const __bf16* kr = &ldsK[(t * 16 + l16) * 64];
            bf16x8 kf0 = *(const bf16x8*)(kr + ((quad ^ swz) * 8));
            bf16x8 kf1 = *(const bf16x8*)(kr + (((quad + 4) ^ swz) * 8));
            st[t] = mfma16(kf0, qf0, z);
            st[t] = mfma16(kf1, qf1, st[t]);
        }
        __builtin_amdgcn_s_setprio(0);

        // scores (log2 domain, scale pre-folded into Q);
        // lane holds keys {16t+quad*4+i} for q=q0+l16
        float a[16];
        #pragma unroll
        for (int t = 0; t < 4; ++t)
            #pragma unroll
            for (int i = 0; i < 4; ++i) {
                float v = st[t][i];
                if (last) {
                    int kidx = t * 16 + quad * 4 + i;      // key - k0
                    v = (kidx <= wiw * 16 + l16) ? v : -1e30f;
                }
                a[t * 4 + i] = v;
            }

        // row max: max3-shaped tree + 2 cross-quad shuffles
        float m0 = fmaxf(fmaxf(a[0],  a[1]),  a[2]);
        float m1 = fmaxf(fmaxf(a[3],  a[4]),  a[5]);
        float m2 = fmaxf(fmaxf(a[6],  a[7]),  a[8]);
        float m3 = fmaxf(fmaxf(a[9],  a[10]), a[11]);
        float m4 = fmaxf(fmaxf(a[12], a[13]), a[14]);
        float mx = fmaxf(fmaxf(fmaxf(m0, m1), m2),
                         fmaxf(fmaxf(m3, m4), a[15]));
        mx = fmaxf(mx, __shfl_xor(mx, 16));
        mx = fmaxf(mx, __shfl_xor(mx, 32));

        // defer-max: only rescale when some row's max grew by >8 (log2 units);
        // otherwise keep m_i, P bounded by 2^8 = 256 (fine in bf16/f32).
        if (__any(mx > m_i + 8.0f)) {
            float mn    = fmaxf(m_i, mx);
            float alpha = exp2v(m_i - mn);
            #pragma unroll
            for (int s = 0; s < 4; ++s)
                #pragma unroll
                for (int i = 0; i < 4; ++i) o[s][i] *= alpha;
            #pragma unroll
            for (int i = 0; i < 4; ++i) lacc[i] *= alpha;
            m_i = mn;
        }

        float p[16];
        #pragma unroll
        for (int j = 0; j < 16; ++j) p[j] = exp2v(a[j] - m_i);

        // P: C-layout -> LDS -> B-layout (per-wave region, stride 72)
        #pragma unroll
        for (int t = 0; t < 4; ++t) {
            bf16x4 pk;
            pk.x = (__bf16)p[t * 4 + 0]; pk.y = (__bf16)p[t * 4 + 1];
            pk.z = (__bf16)p[t * 4 + 2]; pk.w = (__bf16)p[t * 4 + 3];
            *(bf16x4*)(myp + l16 * 72 + t * 16 + quad * 4) = pk;
        }
        asm volatile("s_waitcnt lgkmcnt(0)" ::: "memory");
        bf16x8 pf0 = *(const bf16x8*)(myp + l16 * 72 + quad * 8);
        bf16x8 pf1 = *(const bf16x8*)(myp + l16 * 72 + 32 + quad * 8);

        __builtin_amdgcn_s_setprio(1);
        // row-sum via ones-MFMA: lacc rows all = sum_k P[q][k] (bf16 P —
        // consistent with the P used for O, so O/l is a true weighted mean)
        lacc = mfma16(ones, pf0, lacc);
        lacc = mfma16(ones, pf1, lacc);

        // O^T += V^T P^T : A=V^T (m=d, k=key) from LDS (swizzled)
        #pragma unroll
        for (int s = 0; s < 4; ++s) {
            const __bf16* vr = &ldsV[(s * 16 + l16) * 64];
            bf16x8 vf0 = *(const bf16x8*)(vr + ((quad ^ swz) * 8));
            bf16x8 vf1 = *(const bf16x8*)(vr + (((quad + 4) ^ swz) * 8));
            o[s] = mfma16(vf0, pf0, o[s]);
            o[s] = mfma16(vf1, pf1, o[s]);
        }
        __builtin_amdgcn_s_setprio(0);
        __syncthreads();                        // all waves done with K/V tile

        rk0 = nk0; rk1 = nk1; rv0 = nv0; rv1 = nv1;
    }

    // Epilogue: O^T tile s: row = d = s*16+quad*4+i, col = q = q0+l16
    const float inv = 1.0f / lacc[0];           // all lacc rows identical
    const int bi = bh >> 4, h = bh & 15;
    #pragma unroll
    for (int s = 0; s < 4; ++s) {
        bf16x4 ov;
        ov.x = (__bf16)(o[s][0] * inv); ov.y = (__bf16)(o[s][1] * inv);
        ov.z = (__bf16)(o[s][2] * inv); ov.w = (__bf16)(o[s][3] * inv);
        *(bf16x4*)(aout + ((size_t)(bi * Nseq + q0 + l16)) * Dmod
                   + h * 64 + s * 16 + quad * 4) = ov;
    }
}

// ---------------------------------------------------------------------------
// Kernel 3: output projection — PROVEN R1 version (BM=64 x BN=128, BK=32,
// single-buffer). Grid 64 m-tiles x 8 n-tiles = 512 blocks = 2 blocks/CU.
// ---------------------------------------------------------------------------
__global__ __launch_bounds__(256) void proj_kernel(
    const __bf16* __restrict__ ao, const __bf16* __restrict__ Wo,
    const float* __restrict__ bo, float* __restrict__ out)
{
    __shared__ __align__(16) __bf16 ldsA[64 * 32];
    __shared__ __align__(16) __bf16 ldsB[128 * 32];

    const int tid  = threadIdx.x;
    const int lane = tid & 63, l16 = lane & 15, quad = lane >> 4;
    const int wiw  = tid >> 6;
    const int wm   = wiw & 1, wn = wiw >> 1;

    const int bm = blockIdx.x & 63;             // 64 m-tiles (M=4096, BM=64)
    const int bn = blockIdx.x >> 6;             // 8 n-tiles (N=1024, BN=128)
    const int m0 = bm * 64, n0 = bn * 128;

    const int srow = tid >> 2;                  // 0..63
    const int scol = (tid & 3) * 8;             // {0,8,16,24}

    floatx4 z = {0.f, 0.f, 0.f, 0.f};
    floatx4 acc[2][4];
    #pragma unroll
    for (int mt = 0; mt < 2; ++mt)
        #pragma unroll
        for (int nt = 0; nt < 4; ++nt) acc[mt][nt] = z;

    const __bf16* ga = ao + (size_t)m0 * Dmod;
    const __bf16* gb = Wo + (size_t)n0 * Dmod;

    for (int k0 = 0; k0 < Dmod; k0 += 32) {
        async_copy16(&ldsA[srow * 32 + scol],        ga + (size_t)srow * Dmod + k0 + scol);
        async_copy16(&ldsB[srow * 32 + scol],        gb + (size_t)srow * Dmod + k0 + scol);
        async_copy16(&ldsB[(64 + srow) * 32 + scol], gb + (size_t)(64 + srow) * Dmod + k0 + scol);
        __syncthreads();

        bf16x8 af[2], bfr[4];
        #pragma unroll
        for (int mt = 0; mt < 2; ++mt)
            af[mt] = *(const bf16x8*)&ldsA[(wm * 32 + mt * 16 + l16) * 32 + quad * 8];
        #pragma unroll
        for (int nt = 0; nt < 4; ++nt)
            bfr[nt] = *(const bf16x8*)&ldsB[(wn * 64 + nt * 16 + l16) * 32 + quad * 8];
        #pragma unroll
        for (int mt = 0; mt < 2; ++mt)
            #pragma unroll
            for (int nt = 0; nt < 4; ++nt)
                acc[mt][nt] = mfma16(af[mt], bfr[nt], acc[mt][nt]);
        __syncthreads();
    }

    const int nb = n0 + wn * 64;
    const int mw = m0 + wm * 32;
    #pragma unroll
    for (int nt = 0; nt < 4; ++nt) {
        float bias = bo[nb + nt * 16 + l16];
        #pragma unroll
        for (int mt = 0; mt < 2; ++mt)
            #pragma unroll
            for (int i = 0; i < 4; ++i) {
                int m = mw + mt * 16 + quad * 4 + i;
                out[(size_t)m * Dmod + nb + nt * 16 + l16] = acc[mt][nt][i] + bias;
            }
    }
}

// ---------------------------------------------------------------------------
extern "C" void kernel_launch(void* const* d_in, const int* in_sizes, int n_in,
                              void* d_out, int out_size, void* d_ws, size_t ws_size,
                              hipStream_t stream) {
    const float* x  = (const float*)d_in[0];
    const float* Wq = (const float*)d_in[1];
    const float* bq = (const float*)d_in[2];
    const float* Wo = (const float*)d_in[3];
    const float* bo = (const float*)d_in[4];
    float* out = (float*)d_out;

    __bf16* ws  = (__bf16*)d_ws;
    __bf16* xb  = ws;
    __bf16* wqb = ws + (size_t)XN;
    __bf16* wob = wqb + (size_t)WQN;
    __bf16* qb  = wob + (size_t)WON;
    const size_t SZ = (size_t)Bdim * Hn * Nseq * HDim;
    __bf16* kb  = qb + SZ;
    __bf16* vt  = kb + SZ;
    __bf16* ao  = vt + SZ;

    // 8.38M elems / 8 per thread / 256 = 4096 blocks
    convert_kernel<<<dim3(4096), dim3(256), 0, stream>>>(x, Wq, Wo, xb, wqb, wob);
    // 32 m-tiles x 24 n-tiles = 768 blocks (proven 128x128 tile, BK=32)
    qkv_kernel<<<dim3(768), dim3(256), 0, stream>>>(xb, wqb, bq, qb, kb, vt);
    // 32 bh x 32 q-blocks = 1024 blocks, 4 waves each, balanced remap
    attn_kernel<<<dim3(1024), dim3(256), 0, stream>>>(qb, kb, vt, ao);
    // 64 m-tiles x 8 n-tiles = 512 blocks (2 blocks/CU)
    proj_kernel<<<dim3(512), dim3(256), 0, stream>>>(ao, wob, bo, out);
}

// Round 11
// 165.704 us; speedup vs baseline: 1.3815x; 1.0056x over previous
//
#include <hip/hip_runtime.h>
#include <hip/hip_bf16.h>

// Problem constants
#define Bdim 2
#define Nseq 2048
#define Dmod 1024
#define Hn   16
#define HDim 64

#define XN  (Bdim * Nseq * Dmod)        // 4,194,304
#define WQN (3 * Dmod * Dmod)           // 3,145,728
#define WON (Dmod * Dmod)               // 1,048,576

typedef __attribute__((ext_vector_type(8))) __bf16 bf16x8;
typedef __attribute__((ext_vector_type(4))) __bf16 bf16x4;
typedef __attribute__((ext_vector_type(4))) float  floatx4;

__device__ __forceinline__ floatx4 mfma16(bf16x8 a, bf16x8 b, floatx4 c) {
    return __builtin_amdgcn_mfma_f32_16x16x32_bf16(a, b, c, 0, 0, 0);
}

// native v_exp_f32 computes 2^x
__device__ __forceinline__ float exp2v(float x) {
    return __builtin_amdgcn_exp2f(x);
}

// async global->LDS, 16 B per lane (GEMMs only; attn uses swizzled ds_write).
__device__ __forceinline__ void async_copy16(__bf16* l, const __bf16* g) {
    __builtin_amdgcn_global_load_lds(
        (const __attribute__((address_space(1))) void*)g,
        (__attribute__((address_space(3))) void*)l,
        16, 0, 0);
}

// ---------------------------------------------------------------------------
// Kernel 0: fp32 -> bf16 conversion. 8 elems/thread: 2x float4 load (32 B)
// + 1x bf16x8 store (16 B/lane = coalescing sweet spot).
// ---------------------------------------------------------------------------
__global__ __launch_bounds__(256) void convert_kernel(
    const float* __restrict__ x, const float* __restrict__ wq,
    const float* __restrict__ wo,
    __bf16* __restrict__ xb, __bf16* __restrict__ wqb, __bf16* __restrict__ wob)
{
    int i = (blockIdx.x * 256 + threadIdx.x) * 8;
    const float* src;
    __bf16* dst;
    int off;
    if (i < XN)            { src = x;  dst = xb;  off = i; }
    else if (i < XN + WQN) { src = wq; dst = wqb; off = i - XN; }
    else                   { src = wo; dst = wob; off = i - XN - WQN; }
    float4 v0 = *(const float4*)(src + off);
    float4 v1 = *(const float4*)(src + off + 4);
    bf16x8 o;
    o[0] = (__bf16)v0.x; o[1] = (__bf16)v0.y; o[2] = (__bf16)v0.z; o[3] = (__bf16)v0.w;
    o[4] = (__bf16)v1.x; o[5] = (__bf16)v1.y; o[6] = (__bf16)v1.z; o[7] = (__bf16)v1.w;
    *(bf16x8*)(dst + off) = o;
}

// ---------------------------------------------------------------------------
// Kernel 1: QKV projection — PROVEN R10 version (m97-style 128x128, BK=32,
// single-buffer, bm-fast mapping). Store packing:
//  - V^T (which==2): bf16x4 packed store (R9).
//  - Q/K: PERMUTED-hd layout hd -> l16*4 + nt (R10); permutation cancels in
//    QK^T's contraction since both Q and K carry it. V stays canonical.
// Q third pre-scaled by C = hd^-0.5 * log2(e) (attention runs in log2 domain).
// ---------------------------------------------------------------------------
__global__ __launch_bounds__(256) void qkv_kernel(
    const __bf16* __restrict__ x, const __bf16* __restrict__ Wq,
    const float* __restrict__ bq,
    __bf16* __restrict__ qb, __bf16* __restrict__ kb, __bf16* __restrict__ vt)
{
    __shared__ __align__(16) __bf16 ldsA[128 * 32];
    __shared__ __align__(16) __bf16 ldsB[128 * 32];

    const int tid  = threadIdx.x;
    const int lane = tid & 63, l16 = lane & 15, quad = lane >> 4;
    const int wiw  = tid >> 6;
    const int wm   = wiw & 1, wn = wiw >> 1;

    const int bm = blockIdx.x & 31;             // 32 m-tiles (M=4096)
    const int bn = blockIdx.x >> 5;             // 24 n-tiles (N=3072)
    const int m0 = bm * 128, n0 = bn * 128;

    const int srow = tid >> 2;                  // staging row 0..63
    const int scol = (tid & 3) * 8;             // staging col {0,8,16,24}

    floatx4 z = {0.f, 0.f, 0.f, 0.f};
    floatx4 acc[4][4];
    #pragma unroll
    for (int mt = 0; mt < 4; ++mt)
        #pragma unroll
        for (int nt = 0; nt < 4; ++nt) acc[mt][nt] = z;

    const __bf16* ga = x  + (size_t)m0 * Dmod;
    const __bf16* gb = Wq + (size_t)n0 * Dmod;

    for (int k0 = 0; k0 < Dmod; k0 += 32) {
        async_copy16(&ldsA[srow * 32 + scol],        ga + (size_t)srow * Dmod + k0 + scol);
        async_copy16(&ldsA[(64 + srow) * 32 + scol], ga + (size_t)(64 + srow) * Dmod + k0 + scol);
        async_copy16(&ldsB[srow * 32 + scol],        gb + (size_t)srow * Dmod + k0 + scol);
        async_copy16(&ldsB[(64 + srow) * 32 + scol], gb + (size_t)(64 + srow) * Dmod + k0 + scol);
        __syncthreads();

        bf16x8 af[4], bfr[4];
        #pragma unroll
        for (int mt = 0; mt < 4; ++mt)
            af[mt] = *(const bf16x8*)&ldsA[(wm * 64 + mt * 16 + l16) * 32 + quad * 8];
        #pragma unroll
        for (int nt = 0; nt < 4; ++nt)
            bfr[nt] = *(const bf16x8*)&ldsB[(wn * 64 + nt * 16 + l16) * 32 + quad * 8];
        #pragma unroll
        for (int mt = 0; mt < 4; ++mt)
            #pragma unroll
            for (int nt = 0; nt < 4; ++nt)
                acc[mt][nt] = mfma16(af[mt], bfr[nt], acc[mt][nt]);
        __syncthreads();
    }

    const int nb    = n0 + wn * 64;
    const int which = nb >> 10;
    const int h     = (nb & 1023) >> 6;
    const int mw    = m0 + wm * 64;
    const int bi    = mw >> 11;
    const int pos0  = mw & (Nseq - 1);

    const float qscale = 0.18033688f;           // 0.125 * log2(e)

    float bias4[4];
    #pragma unroll
    for (int nt = 0; nt < 4; ++nt) bias4[nt] = bq[nb + nt * 16 + l16];

    if (which == 2) {
        // V^T: canonical layout; pos varies with i -> packed bf16x4 store
        #pragma unroll
        for (int nt = 0; nt < 4; ++nt) {
            int hd = nt * 16 + l16;
            #pragma unroll
            for (int mt = 0; mt < 4; ++mt) {
                int pos = pos0 + mt * 16 + quad * 4;
                bf16x4 vv;
                vv.x = (__bf16)(acc[mt][nt][0] + bias4[nt]);
                vv.y = (__bf16)(acc[mt][nt][1] + bias4[nt]);
                vv.z = (__bf16)(acc[mt][nt][2] + bias4[nt]);
                vv.w = (__bf16)(acc[mt][nt][3] + bias4[nt]);
                *(bf16x4*)(vt + ((size_t)((bi * Hn + h) * HDim + hd)) * Nseq + pos) = vv;
            }
        }
    } else {
        // Q/K: permuted-hd layout (hd -> l16*4 + nt); lane's 4 nt-values
        // are consecutive -> one aligned 8B store per (mt,i).
        __bf16* dst = (which == 0) ? qb : kb;
        const float sc = (which == 0) ? qscale : 1.0f;
        #pragma unroll
        for (int mt = 0; mt < 4; ++mt)
            #pragma unroll
            for (int i = 0; i < 4; ++i) {
                int pos = pos0 + mt * 16 + quad * 4 + i;
                bf16x4 qk;
                qk.x = (__bf16)((acc[mt][0][i] + bias4[0]) * sc);
                qk.y = (__bf16)((acc[mt][1][i] + bias4[1]) * sc);
                qk.z = (__bf16)((acc[mt][2][i] + bias4[2]) * sc);
                qk.w = (__bf16)((acc[mt][3][i] + bias4[3]) * sc);
                *(bf16x4*)(dst + ((size_t)((bi * Hn + h) * Nseq + pos)) * HDim
                           + l16 * 4) = qk;
            }
    }
}

// ---------------------------------------------------------------------------
// Kernel 2: causal flash attention, block-cooperative — PROVEN R1 version
// (38.5us). Q/K rows arrive in permuted-hd order (see qkv); all reads here
// are byte-linear over the contracted dim, so the permutation cancels
// between the Q and K fragments inside QK^T. V is canonical. Every
// structural deviation regressed (R3/R5/R7); this design's full-tile-body
// register prefetch + 4 blocks/CU matches the latency-hiding budget.
// ---------------------------------------------------------------------------
__global__ __launch_bounds__(256, 4) void attn_kernel(
    const __bf16* __restrict__ qbuf, const __bf16* __restrict__ kbuf,
    const __bf16* __restrict__ vtbuf, __bf16* __restrict__ aout)
{
    __shared__ __align__(16) __bf16 ldsK[64 * 64];   // [key][d], swizzled
    __shared__ __align__(16) __bf16 ldsV[64 * 64];   // [d][key], swizzled
    __shared__ __align__(16) __bf16 ldsP[4][16 * 72];

    const int tid  = threadIdx.x;
    const int wiw  = tid >> 6;
    const int lane = tid & 63, l16 = lane & 15, quad = lane >> 4;
    const int b    = blockIdx.x;
    const int bh   = b & 31;                    // head: all 32 q-blocks of a
                                                // head share one XCD (b%8)
    // Balanced qblk remap: CU hosts blocks {i, i+256, i+512, i+768} ->
    // g-groups {k, k+8, k+16, k+24} -> qblk {31-k, k, 23-k, 8+k},
    // per-CU work = (32-k)+(k+1)+(24-k)+(9+k) = 66 tiles for every k.
    const int g  = b >> 5;
    const int gk = g & 7, r4 = g >> 3;
    int qblk;
    if      (r4 == 0) qblk = 31 - gk;
    else if (r4 == 1) qblk = gk;
    else if (r4 == 2) qblk = 23 - gk;
    else              qblk = 8 + gk;

    const int q0 = qblk * 64 + wiw * 16;        // this wave's 16 queries

    const __bf16* qs = qbuf  + bh * Nseq * HDim;
    const __bf16* ks = kbuf  + bh * Nseq * HDim;
    const __bf16* vs = vtbuf + bh * HDim * Nseq;

    // staging coords: thread handles rows sr, sr+32; 16B block sb
    const int sr  = tid >> 3;                   // 0..31
    const int sb  = tid & 7;                    // 0..7
    const int swr = (sb ^ (sr & 7)) * 8;        // swizzled block offset (elems)
    const int wk0 = sr * 64 + swr;              // (sr+32)&7 == sr&7
    const int wk1 = (sr + 32) * 64 + swr;

    // Q as B-operand: lane l16 = q row, k = permuted-hd = quad*8+j
    bf16x8 qf0 = *(const bf16x8*)(qs + (q0 + l16) * HDim + quad * 8);
    bf16x8 qf1 = *(const bf16x8*)(qs + (q0 + l16) * HDim + 32 + quad * 8);

    floatx4 z = {0.f, 0.f, 0.f, 0.f};
    floatx4 o[4];
    #pragma unroll
    for (int s = 0; s < 4; ++s) o[s] = z;
    floatx4 lacc = z;                           // row-sum accumulator (ones-MFMA)
    float m_i = -1e30f;                         // per-lane: q = q0 + l16

    bf16x8 ones;
    #pragma unroll
    for (int j = 0; j < 8; ++j) ones[j] = (__bf16)1.0f;

    const int   nkt = qblk + 1;                 // 64-key tiles (uniform in block)
    __bf16* myp = ldsP[wiw];
    const int swz = l16 & 7;                    // read-side swizzle (row&7)

    // prefetch tile 0 into registers
    float4 rk0 = *(const float4*)(ks + (size_t)sr * HDim + sb * 8);
    float4 rk1 = *(const float4*)(ks + (size_t)(sr + 32) * HDim + sb * 8);
    float4 rv0 = *(const float4*)(vs + (size_t)sr * Nseq + sb * 8);
    float4 rv1 = *(const float4*)(vs + (size_t)(sr + 32) * Nseq + sb * 8);

    for (int kt = 0; kt < nkt; ++kt) {
        // issue next tile's global loads first (in flight during compute)
        float4 nk0 = {}, nk1 = {}, nv0 = {}, nv1 = {};
        if (kt + 1 < nkt) {
            const int k0n = (kt + 1) * 64;
            nk0 = *(const float4*)(ks + (size_t)(k0n + sr) * HDim + sb * 8);
            nk1 = *(const float4*)(ks + (size_t)(k0n + sr + 32) * HDim + sb * 8);
            nv0 = *(const float4*)(vs + (size_t)sr * Nseq + k0n + sb * 8);
            nv1 = *(const float4*)(vs + (size_t)(sr + 32) * Nseq + k0n + sb * 8);
        }

        // write current tile to LDS (swizzled)
        *(float4*)&ldsK[wk0] = rk0;
        *(float4*)&ldsK[wk1] = rk1;
        *(float4*)&ldsV[wk0] = rv0;
        *(float4*)&ldsV[wk1] = rv1;
        __syncthreads();

        const bool last = (kt == nkt - 1);

        // S^T: 4 subtiles of 16 keys. A=K (m=key), B=Q (n=q).
        floatx4 st[4];
        __builtin_amdgcn_s_setprio(1);
        #pragma unroll
        for (int t = 0; t < 4; ++t) {
            const __bf16* kr = &ldsK[(t * 16 + l16) * 64];
            bf16x8 kf0 = *(const bf16x8*)(kr + ((quad ^ swz) * 8));
            bf16x8 kf1 = *(const bf16x8*)(kr + (((quad + 4) ^ swz) * 8));
            st[t] = mfma16(kf0, qf0, z);
            st[t] = mfma16(kf1, qf1, st[t]);
        }
        __builtin_amdgcn_s_setprio(0);

        // scores (log2 domain, scale pre-folded into Q);
        // lane holds keys {16t+quad*4+i} for q=q0+l16
        float a[16];
        #pragma unroll
        for (int t = 0; t < 4; ++t)
            #pragma unroll
            for (int i = 0; i < 4; ++i) {
                float v = st[t][i];
                if (last) {
                    int kidx = t * 16 + quad * 4 + i;      // key - k0
                    v = (kidx <= wiw * 16 + l16) ? v : -1e30f;
                }
                a[t * 4 + i] = v;
            }

        // row max: max3-shaped tree + 2 cross-quad shuffles
        float m0 = fmaxf(fmaxf(a[0],  a[1]),  a[2]);
        float m1 = fmaxf(fmaxf(a[3],  a[4]),  a[5]);
        float m2 = fmaxf(fmaxf(a[6],  a[7]),  a[8]);
        float m3 = fmaxf(fmaxf(a[9],  a[10]), a[11]);
        float m4 = fmaxf(fmaxf(a[12], a[13]), a[14]);
        float mx = fmaxf(fmaxf(fmaxf(m0, m1), m2),
                         fmaxf(fmaxf(m3, m4), a[15]));
        mx = fmaxf(mx, __shfl_xor(mx, 16));
        mx = fmaxf(mx, __shfl_xor(mx, 32));

        // defer-max: only rescale when some row's max grew by >8 (log2 units);
        // otherwise keep m_i, P bounded by 2^8 = 256 (fine in bf16/f32).
        if (__any(mx > m_i + 8.0f)) {
            float mn    = fmaxf(m_i, mx);
            float alpha = exp2v(m_i - mn);
            #pragma unroll
            for (int s = 0; s < 4; ++s)
                #pragma unroll
                for (int i = 0; i < 4; ++i) o[s][i] *= alpha;
            #pragma unroll
            for (int i = 0; i < 4; ++i) lacc[i] *= alpha;
            m_i = mn;
        }

        float p[16];
        #pragma unroll
        for (int j = 0; j < 16; ++j) p[j] = exp2v(a[j] - m_i);

        // P: C-layout -> LDS -> B-layout (per-wave region, stride 72)
        #pragma unroll
        for (int t = 0; t < 4; ++t) {
            bf16x4 pk;
            pk.x = (__bf16)p[t * 4 + 0]; pk.y = (__bf16)p[t * 4 + 1];
            pk.z = (__bf16)p[t * 4 + 2]; pk.w = (__bf16)p[t * 4 + 3];
            *(bf16x4*)(myp + l16 * 72 + t * 16 + quad * 4) = pk;
        }
        asm volatile("s_waitcnt lgkmcnt(0)" ::: "memory");
        bf16x8 pf0 = *(const bf16x8*)(myp + l16 * 72 + quad * 8);
        bf16x8 pf1 = *(const bf16x8*)(myp + l16 * 72 + 32 + quad * 8);

        __builtin_amdgcn_s_setprio(1);
        // row-sum via ones-MFMA: lacc rows all = sum_k P[q][k] (bf16 P —
        // consistent with the P used for O, so O/l is a true weighted mean)
        lacc = mfma16(ones, pf0, lacc);
        lacc = mfma16(ones, pf1, lacc);

        // O^T += V^T P^T : A=V^T (m=d, k=key) from LDS (swizzled)
        #pragma unroll
        for (int s = 0; s < 4; ++s) {
            const __bf16* vr = &ldsV[(s * 16 + l16) * 64];
            bf16x8 vf0 = *(const bf16x8*)(vr + ((quad ^ swz) * 8));
            bf16x8 vf1 = *(const bf16x8*)(vr + (((quad + 4) ^ swz) * 8));
            o[s] = mfma16(vf0, pf0, o[s]);
            o[s] = mfma16(vf1, pf1, o[s]);
        }
        __builtin_amdgcn_s_setprio(0);
        __syncthreads();                        // all waves done with K/V tile

        rk0 = nk0; rk1 = nk1; rv0 = nv0; rv1 = nv1;
    }

    // Epilogue: O^T tile s: row = d = s*16+quad*4+i, col = q = q0+l16
    const float inv = 1.0f / lacc[0];           // all lacc rows identical
    const int bi = bh >> 4, h = bh & 15;
    #pragma unroll
    for (int s = 0; s < 4; ++s) {
        bf16x4 ov;
        ov.x = (__bf16)(o[s][0] * inv); ov.y = (__bf16)(o[s][1] * inv);
        ov.z = (__bf16)(o[s][2] * inv); ov.w = (__bf16)(o[s][3] * inv);
        *(bf16x4*)(aout + ((size_t)(bi * Nseq + q0 + l16)) * Dmod
                   + h * 64 + s * 16 + quad * 4) = ov;
    }
}

// ---------------------------------------------------------------------------
// Kernel 3: output projection — R11: BM=64 x BN=64 retile for occupancy.
// proj's prior BM=128->64 retile (+1 block/CU) measured -4.5us, showing
// occupancy is its binding constraint. 64x64 -> grid 64m x 16n = 1024
// blocks = 4 blocks/CU (was 2). Per wave: 2x2 acc (32x32 output). Same
// copy16 staging pattern, same bm-fast ordering (co-resident blocks share
// near bn -> B panels L2-resident). LDS 8 KB.
// ---------------------------------------------------------------------------
__global__ __launch_bounds__(256) void proj_kernel(
    const __bf16* __restrict__ ao, const __bf16* __restrict__ Wo,
    const float* __restrict__ bo, float* __restrict__ out)
{
    __shared__ __align__(16) __bf16 ldsA[64 * 32];
    __shared__ __align__(16) __bf16 ldsB[64 * 32];

    const int tid  = threadIdx.x;
    const int lane = tid & 63, l16 = lane & 15, quad = lane >> 4;
    const int wiw  = tid >> 6;
    const int wm   = wiw & 1, wn = (wiw >> 1) & 1;

    const int bm = blockIdx.x & 63;             // 64 m-tiles (M=4096, BM=64)
    const int bn = blockIdx.x >> 6;             // 16 n-tiles (N=1024, BN=64)
    const int m0 = bm * 64, n0 = bn * 64;

    const int srow = tid >> 2;                  // 0..63
    const int scol = (tid & 3) * 8;             // {0,8,16,24}

    floatx4 z = {0.f, 0.f, 0.f, 0.f};
    floatx4 acc[2][2];
    #pragma unroll
    for (int mt = 0; mt < 2; ++mt)
        #pragma unroll
        for (int nt = 0; nt < 2; ++nt) acc[mt][nt] = z;

    const __bf16* ga = ao + (size_t)m0 * Dmod;
    const __bf16* gb = Wo + (size_t)n0 * Dmod;

    for (int k0 = 0; k0 < Dmod; k0 += 32) {
        async_copy16(&ldsA[srow * 32 + scol], ga + (size_t)srow * Dmod + k0 + scol);
        async_copy16(&ldsB[srow * 32 + scol], gb + (size_t)srow * Dmod + k0 + scol);
        __syncthreads();

        bf16x8 af[2], bfr[2];
        #pragma unroll
        for (int mt = 0; mt < 2; ++mt)
            af[mt] = *(const bf16x8*)&ldsA[(wm * 32 + mt * 16 + l16) * 32 + quad * 8];
        #pragma unroll
        for (int nt = 0; nt < 2; ++nt)
            bfr[nt] = *(const bf16x8*)&ldsB[(wn * 32 + nt * 16 + l16) * 32 + quad * 8];
        #pragma unroll
        for (int mt = 0; mt < 2; ++mt)
            #pragma unroll
            for (int nt = 0; nt < 2; ++nt)
                acc[mt][nt] = mfma16(af[mt], bfr[nt], acc[mt][nt]);
        __syncthreads();
    }

    const int nb = n0 + wn * 32;
    const int mw = m0 + wm * 32;
    #pragma unroll
    for (int nt = 0; nt < 2; ++nt) {
        float bias = bo[nb + nt * 16 + l16];
        #pragma unroll
        for (int mt = 0; mt < 2; ++mt)
            #pragma unroll
            for (int i = 0; i < 4; ++i) {
                int m = mw + mt * 16 + quad * 4 + i;
                out[(size_t)m * Dmod + nb + nt * 16 + l16] = acc[mt][nt][i] + bias;
            }
    }
}

// ---------------------------------------------------------------------------
extern "C" void kernel_launch(void* const* d_in, const int* in_sizes, int n_in,
                              void* d_out, int out_size, void* d_ws, size_t ws_size,
                              hipStream_t stream) {
    const float* x  = (const float*)d_in[0];
    const float* Wq = (const float*)d_in[1];
    const float* bq = (const float*)d_in[2];
    const float* Wo = (const float*)d_in[3];
    const float* bo = (const float*)d_in[4];
    float* out = (float*)d_out;

    __bf16* ws  = (__bf16*)d_ws;
    __bf16* xb  = ws;
    __bf16* wqb = ws + (size_t)XN;
    __bf16* wob = wqb + (size_t)WQN;
    __bf16* qb  = wob + (size_t)WON;
    const size_t SZ = (size_t)Bdim * Hn * Nseq * HDim;
    __bf16* kb  = qb + SZ;
    __bf16* vt  = kb + SZ;
    __bf16* ao  = vt + SZ;

    // 8.38M elems / 8 per thread / 256 = 4096 blocks
    convert_kernel<<<dim3(4096), dim3(256), 0, stream>>>(x, Wq, Wo, xb, wqb, wob);
    // 32 m-tiles x 24 n-tiles = 768 blocks (proven 128x128 tile, BK=32)
    qkv_kernel<<<dim3(768), dim3(256), 0, stream>>>(xb, wqb, bq, qb, kb, vt);
    // 32 bh x 32 q-blocks = 1024 blocks, 4 waves each, balanced remap
    attn_kernel<<<dim3(1024), dim3(256), 0, stream>>>(qb, kb, vt, ao);
    // 64 m-tiles x 16 n-tiles = 1024 blocks (4 blocks/CU)
    proj_kernel<<<dim3(1024), dim3(256), 0, stream>>>(ao, wob, bo, out);
}